// Round 1
// baseline (342.887 us; speedup 1.0000x reference)
//
#include <hip/hip_runtime.h>

// GCN 3-layer + edge scorer for MI355X.
// R2: bucket-binned CSR build. R3: bf16 messages. R4: bf16 MFMA GEMM L1.
// R5: fused L3 aggregate + edge-score dots. R6: packed 4B pairs. R7: L3 GEMM
//     ROWS=32. R8: fixed-capacity buckets. R9: 4-deep gather unroll (TLP>ILP).
// R10/R11: per-node GEMV fused into aggregate epilogues.
// R12: L2 GEMV on MFMA pipe (agg1 fused W2 MFMA), padded LDS.
// R13: degree-sorted node perm (counting sort per bucket in build_csr) so each
//      aggregate block gets equal-degree nodes -> removes the max-of-16 barrier
//      imbalance (~35% idle). 8-deep gather unroll (2x MLP) in all aggregates.
//      Bf frags loaded post-barrier in agg1 to keep gather-phase VGPR low.

typedef unsigned short u16;
typedef short bfrag __attribute__((ext_vector_type(8)));   // 8 bf16 = 4 VGPR
typedef float ffrag __attribute__((ext_vector_type(4)));   // 4 f32 acc

#define BSHIFT 8
#define MAXB   512
#define BIN_CHUNK 4096
#define BCAP   4608   // bucket capacity; counts are 4092 +/- 64 (binomial)

static __device__ __forceinline__ float4 f4add(float4 a, float4 b) {
    return make_float4(a.x + b.x, a.y + b.y, a.z + b.z, a.w + b.w);
}

// fp32 -> bf16 bits, RNE
static __device__ __forceinline__ u16 f2bf(float f) {
    unsigned u = __float_as_uint(f);
    u = (u + 0x7FFFu + ((u >> 16) & 1u)) >> 16;
    return (u16)u;
}

static __device__ __forceinline__ float bflo(unsigned u) {
    return __uint_as_float(u << 16);
}
static __device__ __forceinline__ float bfhi(unsigned u) {
    return __uint_as_float(u & 0xFFFF0000u);
}
static __device__ __forceinline__ void bfacc2(float& a0, float& a1, unsigned u) {
    a0 += bflo(u);
    a1 += bfhi(u);
}
static __device__ __forceinline__ void bfacc8(float* a, uint4 u) {
    bfacc2(a[0], a[1], u.x); bfacc2(a[2], a[3], u.y);
    bfacc2(a[4], a[5], u.z); bfacc2(a[6], a[7], u.w);
}

// ---------------- CSR build ----------------

// pairs packed: (dst & 255) << 24 | src   (src < 2^24)
__global__ __launch_bounds__(256) void bin_edges(const int* __restrict__ src,
                                                 const int* __restrict__ dst,
                                                 int* __restrict__ bcur,
                                                 unsigned* __restrict__ pairs,
                                                 int E, int B) {
    __shared__ int h[MAXB];
    __shared__ int base[MAXB];
    const int t = threadIdx.x;
    const int e0 = blockIdx.x * BIN_CHUNK;
    const int eEnd = min(e0 + BIN_CHUNK, E);
    for (int i = t; i < B; i += 256) h[i] = 0;
    __syncthreads();
    for (int e = e0 + t; e < eEnd; e += 256)
        atomicAdd(&h[dst[e] >> BSHIFT], 1);
    __syncthreads();
    for (int i = t; i < B; i += 256) {
        int c = h[i];
        base[i] = c ? atomicAdd(&bcur[i], c) : 0;
        h[i] = 0;
    }
    __syncthreads();
    for (int e = e0 + t; e < eEnd; e += 256) {
        int d = dst[e];
        int b = d >> BSHIFT;
        int pos = base[b] + atomicAdd(&h[b], 1);
        pairs[pos] = ((unsigned)(d & 255) << 24) | (unsigned)src[e];
    }
}

// one block per bucket; bucket b spans [b*BCAP, bcur[b]) after bin_edges.
// Also emits perm[]: bucket-local counting sort of nodes by in-degree, so
// downstream aggregate blocks (16/32 consecutive perm slots) see near-equal
// degrees. Invalid slots (last bucket tail) get -1.
__global__ __launch_bounds__(256) void build_csr(const unsigned* __restrict__ pairs,
                                                 const int* __restrict__ bcur,
                                                 int* __restrict__ rowp,
                                                 int* __restrict__ rowe,
                                                 float* __restrict__ dinv,
                                                 int* __restrict__ ssrc,
                                                 int* __restrict__ perm, int N) {
    __shared__ int s[256];
    __shared__ int cur[256];
    __shared__ int hcur[64];   // degree histogram -> exclusive base -> cursor
    const int t = threadIdx.x;
    const int b = blockIdx.x;
    const int eBeg = b * BCAP, eEnd = bcur[b];
    const int nodeBase = b << BSHIFT;
    s[t] = 0;
    if (t < 64) hcur[t] = 0;
    __syncthreads();
    for (int e = eBeg + t; e < eEnd; e += 256)
        atomicAdd(&s[pairs[e] >> 24], 1);
    __syncthreads();
    const int v = s[t];
    #pragma unroll
    for (int off = 1; off < 256; off <<= 1) {
        int add = (t >= off) ? s[t - off] : 0;
        __syncthreads();
        s[t] += add;
        __syncthreads();
    }
    const int rp = eBeg + s[t] - v;
    const int node = nodeBase + t;
    const int nvalid = min(N - nodeBase, 256);
    const int dc = min(v, 63);
    if (t < nvalid) {
        rowp[node] = rp;
        rowe[node] = rp + v;
        dinv[node] = rsqrtf((float)(v + 1));
        atomicAdd(&hcur[dc], 1);
    } else {
        perm[(b << 8) + t] = -1;
    }
    cur[t] = rp;
    __syncthreads();
    if (t == 0) {   // exclusive scan of 64-entry histogram (serial, tiny)
        int acc = 0;
        #pragma unroll
        for (int i = 0; i < 64; i++) { int h = hcur[i]; hcur[i] = acc; acc += h; }
    }
    __syncthreads();
    if (t < nvalid) {
        int rank = atomicAdd(&hcur[dc], 1);
        perm[(b << 8) + rank] = node;
    }
    for (int e = eBeg + t; e < eEnd; e += 256) {
        unsigned p = pairs[e];
        int pos = atomicAdd(&cur[p >> 24], 1);
        ssrc[pos] = (int)(p & 0xFFFFFFu);
    }
}

// ---------------- prep: w1t, w2t (both transposed bf16 [n][k] for MFMA),
//                  bucket cursors ----------------
__global__ __launch_bounds__(256) void prep_all(const float* __restrict__ W1,
                                                u16* __restrict__ w1t,
                                                const float* __restrict__ W2,
                                                u16* __restrict__ w2t,
                                                int* __restrict__ bcur, int B) {
    int idx = blockIdx.x * 256 + threadIdx.x;
    if (idx < 128 * 128) {
        int n = idx >> 7, k = idx & 127;
        w1t[idx] = f2bf(W1[k * 128 + n]);          // [n][k] for MFMA B-frags
    } else if (idx < 128 * 128 + 64 * 128) {
        int j = idx - 128 * 128;
        int n = j >> 7, k = j & 127;
        w2t[j] = f2bf(W2[k * 64 + n]);             // [n][k] for MFMA B-frags
    }
    if (idx < B) bcur[idx] = idx * BCAP;
}

// ---------------- MFMA GEMM (layer 1): g1 = bf16((x @ W1) * dinv[row]) ------
template <int FIN, int FOUT, bool AF32, int MINW>
__global__ __launch_bounds__(256, MINW)
void gemm_mfma(const void* __restrict__ Xv, const u16* __restrict__ Wt,
               const float* __restrict__ dinv, u16* __restrict__ G, int N) {
    constexpr int NT = FOUT / 16;
    constexpr int KK = FIN / 32;
    constexpr int CB = FIN / 8;
    constexpr int ITER = (64 * CB) / 256;
    __shared__ __align__(16) u16 xs[64 * FIN];
    __shared__ float ldv[64];

    const int t = threadIdx.x;
    const int wave = t >> 6;
    const int lane = t & 63;
    const int l15 = lane & 15;
    const int quad = lane >> 4;
    const int r0 = blockIdx.x * 64;

    bfrag Bf[NT][KK];
    #pragma unroll
    for (int nt = 0; nt < NT; nt++)
        #pragma unroll
        for (int kk = 0; kk < KK; kk++)
            Bf[nt][kk] = *reinterpret_cast<const bfrag*>(
                &Wt[(size_t)(nt * 16 + l15) * FIN + kk * 32 + quad * 8]);

    if (t < 64) ldv[t] = (r0 + t < N) ? dinv[r0 + t] : 0.f;

    #pragma unroll
    for (int i = 0; i < ITER; i++) {
        int v = t + 256 * i;
        int row = v / CB;
        int cb = v - row * CB;
        uint4 pack = make_uint4(0, 0, 0, 0);
        if (r0 + row < N) {
            if (AF32) {
                const float* X = (const float*)Xv;
                const float4* p = reinterpret_cast<const float4*>(
                    &X[(size_t)(r0 + row) * FIN + cb * 8]);
                float4 lo = p[0], hi = p[1];
                pack.x = f2bf(lo.x) | ((unsigned)f2bf(lo.y) << 16);
                pack.y = f2bf(lo.z) | ((unsigned)f2bf(lo.w) << 16);
                pack.z = f2bf(hi.x) | ((unsigned)f2bf(hi.y) << 16);
                pack.w = f2bf(hi.z) | ((unsigned)f2bf(hi.w) << 16);
            } else {
                const u16* X = (const u16*)Xv;
                pack = *reinterpret_cast<const uint4*>(
                    &X[(size_t)(r0 + row) * FIN + cb * 8]);
            }
        }
        int cbs = cb ^ (row & 7);
        *reinterpret_cast<uint4*>(&xs[row * FIN + cbs * 8]) = pack;
    }
    __syncthreads();

    ffrag acc[NT];
    #pragma unroll
    for (int nt = 0; nt < NT; nt++) {
        acc[nt][0] = 0.f; acc[nt][1] = 0.f; acc[nt][2] = 0.f; acc[nt][3] = 0.f;
    }

    const int arow = wave * 16 + l15;
    #pragma unroll
    for (int kk = 0; kk < KK; kk++) {
        int cb = (kk * 4 + quad) ^ (l15 & 7);
        bfrag a = *reinterpret_cast<const bfrag*>(&xs[arow * FIN + cb * 8]);
        #pragma unroll
        for (int nt = 0; nt < NT; nt++)
            acc[nt] = __builtin_amdgcn_mfma_f32_16x16x32_bf16(a, Bf[nt][kk], acc[nt], 0, 0, 0);
    }

    #pragma unroll
    for (int nt = 0; nt < NT; nt++)
        #pragma unroll
        for (int r = 0; r < 4; r++) {
            int rl = wave * 16 + quad * 4 + r;
            int grow = r0 + rl;
            if (grow < N)
                G[(size_t)grow * FOUT + nt * 16 + l15] = f2bf(acc[nt][r] * ldv[rl]);
        }
}

// ---------------- L1 aggregate + fused L2 GEMM via MFMA ----------------
// h1[d] = relu(dinv*(g1[d]+sum g1[src])+b1)  (bf16, staged in LDS)
// g2 tile = bf16(dinv[m] * (h1 @ W2)): 16 nodes x 64 cols, wave w does its
// 16-col tile with 4x mfma_16x16x32_bf16. Nodes come from perm[] (degree
// sorted) so the pre-MFMA barrier waits ~0.
__global__ __launch_bounds__(256) void agg1_gemm2(const u16* __restrict__ G,
                                                  const int* __restrict__ rowp,
                                                  const int* __restrict__ rowe,
                                                  const int* __restrict__ ssrc,
                                                  const int* __restrict__ perm,
                                                  const float* __restrict__ dinv,
                                                  const float* __restrict__ bias,
                                                  const u16* __restrict__ w2t,
                                                  u16* __restrict__ g2, int N) {
    __shared__ __align__(16) u16 hl[16][136];   // 4.25 KB, padded stride 272B
    __shared__ float ldv[16];
    __shared__ int pn[16];
    const int t = threadIdx.x;
    const int wave = t >> 6;
    const int lane = t & 63;
    const int l15 = lane & 15;
    const int quad = lane >> 4;
    const int lj = t & 15;     // 16 lanes per node (8 features each)
    const int dn = t >> 4;     // node-in-block
    const int d0 = blockIdx.x * 16;

    if (t < 16) {
        int nd = perm[d0 + t];
        pn[t] = nd;
        ldv[t] = (nd >= 0) ? dinv[nd] : 0.f;
    }
    const int d = perm[d0 + dn];   // broadcast load per 16-lane group

    uint4 pk = make_uint4(0, 0, 0, 0);
    if (d >= 0) {
        const uint4* G4 = reinterpret_cast<const uint4*>(G);
        float a[8];
        #pragma unroll
        for (int i = 0; i < 8; i++) a[i] = 0.f;
        bfacc8(a, G4[(size_t)d * 16 + lj]);   // self loop
        int e = rowp[d];
        const int end = rowe[d];
        for (; e + 8 <= end; e += 8) {
            int s0 = ssrc[e],     s1 = ssrc[e + 1], s2 = ssrc[e + 2], s3 = ssrc[e + 3];
            int s4 = ssrc[e + 4], s5 = ssrc[e + 5], s6 = ssrc[e + 6], s7 = ssrc[e + 7];
            uint4 u0 = G4[(size_t)s0 * 16 + lj];
            uint4 u1 = G4[(size_t)s1 * 16 + lj];
            uint4 u2 = G4[(size_t)s2 * 16 + lj];
            uint4 u3 = G4[(size_t)s3 * 16 + lj];
            uint4 u4 = G4[(size_t)s4 * 16 + lj];
            uint4 u5 = G4[(size_t)s5 * 16 + lj];
            uint4 u6 = G4[(size_t)s6 * 16 + lj];
            uint4 u7 = G4[(size_t)s7 * 16 + lj];
            bfacc8(a, u0); bfacc8(a, u1); bfacc8(a, u2); bfacc8(a, u3);
            bfacc8(a, u4); bfacc8(a, u5); bfacc8(a, u6); bfacc8(a, u7);
        }
        for (; e + 4 <= end; e += 4) {
            int s0 = ssrc[e], s1 = ssrc[e + 1], s2 = ssrc[e + 2], s3 = ssrc[e + 3];
            uint4 u0 = G4[(size_t)s0 * 16 + lj];
            uint4 u1 = G4[(size_t)s1 * 16 + lj];
            uint4 u2 = G4[(size_t)s2 * 16 + lj];
            uint4 u3 = G4[(size_t)s3 * 16 + lj];
            bfacc8(a, u0); bfacc8(a, u1); bfacc8(a, u2); bfacc8(a, u3);
        }
        for (; e < end; e++)
            bfacc8(a, G4[(size_t)ssrc[e] * 16 + lj]);
        const float dv = dinv[d];
        const float4 b0 = reinterpret_cast<const float4*>(bias)[lj * 2];
        const float4 b1 = reinterpret_cast<const float4*>(bias)[lj * 2 + 1];
        float h[8];
        h[0] = fmaxf(a[0] * dv + b0.x, 0.f);
        h[1] = fmaxf(a[1] * dv + b0.y, 0.f);
        h[2] = fmaxf(a[2] * dv + b0.z, 0.f);
        h[3] = fmaxf(a[3] * dv + b0.w, 0.f);
        h[4] = fmaxf(a[4] * dv + b1.x, 0.f);
        h[5] = fmaxf(a[5] * dv + b1.y, 0.f);
        h[6] = fmaxf(a[6] * dv + b1.z, 0.f);
        h[7] = fmaxf(a[7] * dv + b1.w, 0.f);
        pk.x = f2bf(h[0]) | ((unsigned)f2bf(h[1]) << 16);
        pk.y = f2bf(h[2]) | ((unsigned)f2bf(h[3]) << 16);
        pk.z = f2bf(h[4]) | ((unsigned)f2bf(h[5]) << 16);
        pk.w = f2bf(h[6]) | ((unsigned)f2bf(h[7]) << 16);
    }
    *reinterpret_cast<uint4*>(&hl[dn][lj * 8]) = pk;
    __syncthreads();

    // B-frags loaded post-barrier: keeps gather-phase VGPR low.
    bfrag Bf[4];
    #pragma unroll
    for (int kk = 0; kk < 4; kk++)
        Bf[kk] = *reinterpret_cast<const bfrag*>(
            &w2t[(size_t)(wave * 16 + l15) * 128 + kk * 32 + quad * 8]);

    // MFMA: A[m=l15][k=quad*8+j] from hl; D: row=quad*4+r, col=l15.
    ffrag acc;
    acc[0] = 0.f; acc[1] = 0.f; acc[2] = 0.f; acc[3] = 0.f;
    #pragma unroll
    for (int kk = 0; kk < 4; kk++) {
        bfrag av = *reinterpret_cast<const bfrag*>(&hl[l15][kk * 32 + quad * 8]);
        acc = __builtin_amdgcn_mfma_f32_16x16x32_bf16(av, Bf[kk], acc, 0, 0, 0);
    }
    #pragma unroll
    for (int r = 0; r < 4; r++) {
        int row = quad * 4 + r;
        int node = pn[row];
        if (node >= 0)
            g2[(size_t)node * 64 + wave * 16 + l15] = f2bf(acc[r] * ldv[row]);
    }
}

// ---------------- L2 aggregate + fused L3 GEMV (fp32) ----------------
// h2[d] = relu(dinv*(g2[d]+sum g2[src])+b2)  (fp32)
// g3[d] = fp32(dinv[d] * (h2[d] @ W3))       (W3 fp32 [k][j] in LDS)
__global__ __launch_bounds__(256) void agg2_gemm3(const u16* __restrict__ G,
                                                  const int* __restrict__ rowp,
                                                  const int* __restrict__ rowe,
                                                  const int* __restrict__ ssrc,
                                                  const int* __restrict__ perm,
                                                  const float* __restrict__ dinv,
                                                  const float* __restrict__ bias,
                                                  const float* __restrict__ W3,
                                                  float* __restrict__ g3, int N) {
    __shared__ __align__(16) float wl[64 * 32];   // 8 KB W3 [k][j]
    __shared__ __align__(16) float hl[32][68];    // padded: stride 272B
    const int t = threadIdx.x;
    {   // cooperative W3 load: 2048 floats = 512 float4
        const float4* s4 = reinterpret_cast<const float4*>(W3);
        float4* d4 = reinterpret_cast<float4*>(wl);
        d4[t] = s4[t];
        d4[t + 256] = s4[t + 256];
    }
    __syncthreads();
    const int lj = t & 7;      // 8 lanes per node (8 features each)
    const int dn = t >> 3;
    const int d = perm[blockIdx.x * 32 + dn];
    if (d < 0) return;

    const uint4* G4 = reinterpret_cast<const uint4*>(G);
    float a[8];
    #pragma unroll
    for (int i = 0; i < 8; i++) a[i] = 0.f;
    bfacc8(a, G4[(size_t)d * 8 + lj]);   // self loop
    int e = rowp[d];
    const int end = rowe[d];
    for (; e + 8 <= end; e += 8) {
        int s0 = ssrc[e],     s1 = ssrc[e + 1], s2 = ssrc[e + 2], s3 = ssrc[e + 3];
        int s4 = ssrc[e + 4], s5 = ssrc[e + 5], s6 = ssrc[e + 6], s7 = ssrc[e + 7];
        uint4 u0 = G4[(size_t)s0 * 8 + lj];
        uint4 u1 = G4[(size_t)s1 * 8 + lj];
        uint4 u2 = G4[(size_t)s2 * 8 + lj];
        uint4 u3 = G4[(size_t)s3 * 8 + lj];
        uint4 u4 = G4[(size_t)s4 * 8 + lj];
        uint4 u5 = G4[(size_t)s5 * 8 + lj];
        uint4 u6 = G4[(size_t)s6 * 8 + lj];
        uint4 u7 = G4[(size_t)s7 * 8 + lj];
        bfacc8(a, u0); bfacc8(a, u1); bfacc8(a, u2); bfacc8(a, u3);
        bfacc8(a, u4); bfacc8(a, u5); bfacc8(a, u6); bfacc8(a, u7);
    }
    for (; e + 4 <= end; e += 4) {
        int s0 = ssrc[e], s1 = ssrc[e + 1], s2 = ssrc[e + 2], s3 = ssrc[e + 3];
        uint4 u0 = G4[(size_t)s0 * 8 + lj];
        uint4 u1 = G4[(size_t)s1 * 8 + lj];
        uint4 u2 = G4[(size_t)s2 * 8 + lj];
        uint4 u3 = G4[(size_t)s3 * 8 + lj];
        bfacc8(a, u0); bfacc8(a, u1); bfacc8(a, u2); bfacc8(a, u3);
    }
    for (; e < end; e++)
        bfacc8(a, G4[(size_t)ssrc[e] * 8 + lj]);
    const float dv = dinv[d];
    const float4 b0 = reinterpret_cast<const float4*>(bias)[lj * 2];
    const float4 b1 = reinterpret_cast<const float4*>(bias)[lj * 2 + 1];
    float h[8];
    h[0] = fmaxf(a[0] * dv + b0.x, 0.f);
    h[1] = fmaxf(a[1] * dv + b0.y, 0.f);
    h[2] = fmaxf(a[2] * dv + b0.z, 0.f);
    h[3] = fmaxf(a[3] * dv + b0.w, 0.f);
    h[4] = fmaxf(a[4] * dv + b1.x, 0.f);
    h[5] = fmaxf(a[5] * dv + b1.y, 0.f);
    h[6] = fmaxf(a[6] * dv + b1.z, 0.f);
    h[7] = fmaxf(a[7] * dv + b1.w, 0.f);
    *reinterpret_cast<float4*>(&hl[dn][lj * 8])     = make_float4(h[0], h[1], h[2], h[3]);
    *reinterpret_cast<float4*>(&hl[dn][lj * 8 + 4]) = make_float4(h[4], h[5], h[6], h[7]);
    // GEMV: 8-lane group intra-wave -> ordered LDS, no barrier.
    float g[4] = {0.f, 0.f, 0.f, 0.f};
    #pragma unroll 4
    for (int k4 = 0; k4 < 16; k4++) {
        float4 hv = *reinterpret_cast<const float4*>(&hl[dn][k4 * 4]);
        float hs[4] = {hv.x, hv.y, hv.z, hv.w};
        #pragma unroll
        for (int p = 0; p < 4; p++) {
            float4 w = *reinterpret_cast<const float4*>(&wl[(k4 * 4 + p) * 32 + lj * 4]);
            g[0] += hs[p] * w.x; g[1] += hs[p] * w.y;
            g[2] += hs[p] * w.z; g[3] += hs[p] * w.w;
        }
    }
    *reinterpret_cast<float4*>(&g3[(size_t)d * 32 + lj * 4]) =
        make_float4(g[0] * dv, g[1] * dv, g[2] * dv, g[3] * dv);
}

// ---------------- L3 aggregate fused with edge-score node dots ----------------
__global__ __launch_bounds__(256) void aggregate_l3s(const float* __restrict__ G,
                                                     const int* __restrict__ rowp,
                                                     const int* __restrict__ rowe,
                                                     const int* __restrict__ ssrc,
                                                     const int* __restrict__ perm,
                                                     const float* __restrict__ dinv,
                                                     const float* __restrict__ bias,
                                                     const float* __restrict__ Wc,
                                                     float2* __restrict__ ab, int N) {
    constexpr int L = 8;
    const int t = threadIdx.x;
    const int lj = t % L;
    const int d = perm[blockIdx.x * 32 + t / L];
    if (d < 0) return;

    const float4* G4 = reinterpret_cast<const float4*>(G);
    float4 acc = G4[(size_t)d * L + lj];
    int e = rowp[d];
    const int end = rowe[d];
    for (; e + 8 <= end; e += 8) {
        int s0 = ssrc[e],     s1 = ssrc[e + 1], s2 = ssrc[e + 2], s3 = ssrc[e + 3];
        int s4 = ssrc[e + 4], s5 = ssrc[e + 5], s6 = ssrc[e + 6], s7 = ssrc[e + 7];
        float4 v0 = G4[(size_t)s0 * L + lj];
        float4 v1 = G4[(size_t)s1 * L + lj];
        float4 v2 = G4[(size_t)s2 * L + lj];
        float4 v3 = G4[(size_t)s3 * L + lj];
        float4 v4 = G4[(size_t)s4 * L + lj];
        float4 v5 = G4[(size_t)s5 * L + lj];
        float4 v6 = G4[(size_t)s6 * L + lj];
        float4 v7 = G4[(size_t)s7 * L + lj];
        acc = f4add(acc, f4add(f4add(f4add(v0, v1), f4add(v2, v3)),
                               f4add(f4add(v4, v5), f4add(v6, v7))));
    }
    for (; e + 4 <= end; e += 4) {
        int s0 = ssrc[e], s1 = ssrc[e + 1], s2 = ssrc[e + 2], s3 = ssrc[e + 3];
        float4 v0 = G4[(size_t)s0 * L + lj];
        float4 v1 = G4[(size_t)s1 * L + lj];
        float4 v2 = G4[(size_t)s2 * L + lj];
        float4 v3 = G4[(size_t)s3 * L + lj];
        acc = f4add(acc, f4add(f4add(v0, v1), f4add(v2, v3)));
    }
    for (; e < end; e++)
        acc = f4add(acc, G4[(size_t)ssrc[e] * L + lj]);
    const float dv = dinv[d];
    const float4 b4 = reinterpret_cast<const float4*>(bias)[lj];
    float4 h;
    h.x = fmaxf(acc.x * dv + b4.x, 0.f);
    h.y = fmaxf(acc.y * dv + b4.y, 0.f);
    h.z = fmaxf(acc.z * dv + b4.z, 0.f);
    h.w = fmaxf(acc.w * dv + b4.w, 0.f);
    const float4 wa = reinterpret_cast<const float4*>(Wc)[lj];
    const float4 wb = reinterpret_cast<const float4*>(Wc + 32)[lj];
    float p = h.x * wa.x + h.y * wa.y + h.z * wa.z + h.w * wa.w;
    float q = h.x * wb.x + h.y * wb.y + h.z * wb.z + h.w * wb.w;
    p += __shfl_xor(p, 1); q += __shfl_xor(q, 1);
    p += __shfl_xor(p, 2); q += __shfl_xor(q, 2);
    p += __shfl_xor(p, 4); q += __shfl_xor(q, 4);
    if (lj == 0) ab[d] = make_float2(p, q);
}

// ---------------- edge output ----------------

__global__ __launch_bounds__(256) void edge_out(const int* __restrict__ src,
                                                const int* __restrict__ dst,
                                                const float2* __restrict__ ab,
                                                const float* __restrict__ bc,
                                                float* __restrict__ out, int E) {
    int e = blockIdx.x * 256 + threadIdx.x;
    if (e < E) out[e] = ab[src[e]].x + ab[dst[e]].y + bc[0];
}

extern "C" void kernel_launch(void* const* d_in, const int* in_sizes, int n_in,
                              void* d_out, int out_size, void* d_ws, size_t ws_size,
                              hipStream_t stream) {
    const float* x  = (const float*)d_in[0];
    const int*   ei = (const int*)d_in[1];
    const float* W1 = (const float*)d_in[2];
    const float* b1 = (const float*)d_in[3];
    const float* W2 = (const float*)d_in[4];
    const float* b2 = (const float*)d_in[5];
    const float* W3 = (const float*)d_in[6];
    const float* b3 = (const float*)d_in[7];
    const float* Wc = (const float*)d_in[8];
    const float* bc = (const float*)d_in[9];
    float* out = (float*)d_out;

    const int N = in_sizes[0] / 128;   // 100000
    const int E = in_sizes[1] / 2;     // 1600000
    const int B = (N + 255) >> BSHIFT; // 391
    const int* src = ei;
    const int* dst = ei + E;

    size_t off = 0;
    auto alloc = [&](size_t bytes) -> void* {
        size_t o = (off + 255) & ~(size_t)255;
        off = o + bytes;
        return (void*)((char*)d_ws + o);
    };
    float* dinv = (float*)alloc((size_t)N * 4);
    int*   rowp = (int*)alloc((size_t)N * 4);
    int*   rowe = (int*)alloc((size_t)N * 4);
    int*   bcur = (int*)alloc((size_t)(B + 1) * 4);
    int*   ssrc = (int*)alloc((size_t)B * BCAP * 4);  // padded CSR storage
    int*   perm = (int*)alloc((size_t)B * 256 * 4);   // degree-sorted node order
    u16*   w1t  = (u16*)alloc(128 * 128 * 2);
    u16*   w2t  = (u16*)alloc(64 * 128 * 2);
    u16*   g16  = (u16*)alloc((size_t)N * 128 * 2);   // L1 messages; g3f alias
    u16*   g2b  = (u16*)alloc((size_t)N * 64 * 2);    // L2 messages; pairs alias
    float2* ab  = (float2*)alloc((size_t)N * 8);
    (void)ws_size; (void)n_in; (void)out_size;

    unsigned* pairs = (unsigned*)g2b;  // 7.2MB pairs, dead before agg1 writes g2b
    float* g3f = (float*)g16;          // g16 dead after agg1_gemm2

    const int gE = (E + 255) / 256;
    const int gR = (N + 63) / 64;   // 1563

    prep_all<<<96, 256, 0, stream>>>(W1, w1t, W2, w2t, bcur, B);
    bin_edges<<<(E + BIN_CHUNK - 1) / BIN_CHUNK, 256, 0, stream>>>(src, dst, bcur, pairs, E, B);
    build_csr<<<B, 256, 0, stream>>>(pairs, bcur, rowp, rowe, dinv, ssrc, perm, N);

    // layer 1 GEMM: x(f32,128) -> MFMA -> g16 (bf16 messages)
    gemm_mfma<128, 128, true, 2><<<gR, 256, 0, stream>>>(x, w1t, dinv, g16, N);
    // L1 aggregate + fused L2 MFMA-GEMM -> g2 (bf16 messages)
    agg1_gemm2<<<B * 16, 256, 0, stream>>>(g16, rowp, rowe, ssrc, perm, dinv, b1, w2t, g2b, N);
    // L2 aggregate + fused L3 GEMV -> g3 (fp32 messages)
    agg2_gemm3<<<B * 8, 256, 0, stream>>>(g2b, rowp, rowe, ssrc, perm, dinv, b2, W3, g3f, N);
    // L3 aggregate + edge-score node dots
    aggregate_l3s<<<B * 8, 256, 0, stream>>>(g3f, rowp, rowe, ssrc, perm, dinv, b3, Wc, ab, N);

    // edge output
    edge_out<<<gE, 256, 0, stream>>>(src, dst, ab, bc, out, E);
}

// Round 2
// 319.423 us; speedup vs baseline: 1.0735x; 1.0735x over previous
//
#include <hip/hip_runtime.h>

// GCN 3-layer + edge scorer for MI355X.
// R2: bucket-binned CSR build. R3: bf16 messages. R4: bf16 MFMA GEMM L1.
// R5: fused L3 aggregate + edge-score dots. R6: packed 4B pairs. R7: L3 GEMM
//     ROWS=32. R8: fixed-capacity buckets. R9: 4-deep gather unroll (TLP>ILP).
// R10/R11: per-node GEMV fused into aggregate epilogues.
// R12: L2 GEMV on MFMA pipe (agg1 fused W2 MFMA), padded LDS.
// R13 (REVERTED): degree-sorted node perm. Scatter-locality cost (+11MB FETCH,
//      occupancy 57->38) exceeded balance gain; agg2/l3s (barrier-free) also
//      regressed -> sorting is net-negative. Natural node order restored.
// R14: isolated 8-deep gather unroll (2x loads in flight per wave) in all
//      three aggregates; summation order unchanged (bit-identical). Bf frags
//      loaded post-barrier in agg1 to keep gather-phase VGPR low.

typedef unsigned short u16;
typedef short bfrag __attribute__((ext_vector_type(8)));   // 8 bf16 = 4 VGPR
typedef float ffrag __attribute__((ext_vector_type(4)));   // 4 f32 acc

#define BSHIFT 8
#define MAXB   512
#define BIN_CHUNK 4096
#define BCAP   4608   // bucket capacity; counts are 4092 +/- 64 (binomial)

static __device__ __forceinline__ float4 f4add(float4 a, float4 b) {
    return make_float4(a.x + b.x, a.y + b.y, a.z + b.z, a.w + b.w);
}

// fp32 -> bf16 bits, RNE
static __device__ __forceinline__ u16 f2bf(float f) {
    unsigned u = __float_as_uint(f);
    u = (u + 0x7FFFu + ((u >> 16) & 1u)) >> 16;
    return (u16)u;
}

static __device__ __forceinline__ float bflo(unsigned u) {
    return __uint_as_float(u << 16);
}
static __device__ __forceinline__ float bfhi(unsigned u) {
    return __uint_as_float(u & 0xFFFF0000u);
}
static __device__ __forceinline__ void bfacc2(float& a0, float& a1, unsigned u) {
    a0 += bflo(u);
    a1 += bfhi(u);
}
static __device__ __forceinline__ void bfacc8(float* a, uint4 u) {
    bfacc2(a[0], a[1], u.x); bfacc2(a[2], a[3], u.y);
    bfacc2(a[4], a[5], u.z); bfacc2(a[6], a[7], u.w);
}

// ---------------- CSR build ----------------

// pairs packed: (dst & 255) << 24 | src   (src < 2^24)
__global__ __launch_bounds__(256) void bin_edges(const int* __restrict__ src,
                                                 const int* __restrict__ dst,
                                                 int* __restrict__ bcur,
                                                 unsigned* __restrict__ pairs,
                                                 int E, int B) {
    __shared__ int h[MAXB];
    __shared__ int base[MAXB];
    const int t = threadIdx.x;
    const int e0 = blockIdx.x * BIN_CHUNK;
    const int eEnd = min(e0 + BIN_CHUNK, E);
    for (int i = t; i < B; i += 256) h[i] = 0;
    __syncthreads();
    for (int e = e0 + t; e < eEnd; e += 256)
        atomicAdd(&h[dst[e] >> BSHIFT], 1);
    __syncthreads();
    for (int i = t; i < B; i += 256) {
        int c = h[i];
        base[i] = c ? atomicAdd(&bcur[i], c) : 0;
        h[i] = 0;
    }
    __syncthreads();
    for (int e = e0 + t; e < eEnd; e += 256) {
        int d = dst[e];
        int b = d >> BSHIFT;
        int pos = base[b] + atomicAdd(&h[b], 1);
        pairs[pos] = ((unsigned)(d & 255) << 24) | (unsigned)src[e];
    }
}

// one block per bucket; bucket b spans [b*BCAP, bcur[b]) after bin_edges.
__global__ __launch_bounds__(256) void build_csr(const unsigned* __restrict__ pairs,
                                                 const int* __restrict__ bcur,
                                                 int* __restrict__ rowp,
                                                 int* __restrict__ rowe,
                                                 float* __restrict__ dinv,
                                                 int* __restrict__ ssrc, int N) {
    __shared__ int s[256];
    __shared__ int cur[256];
    const int t = threadIdx.x;
    const int b = blockIdx.x;
    const int eBeg = b * BCAP, eEnd = bcur[b];
    const int nodeBase = b << BSHIFT;
    s[t] = 0;
    __syncthreads();
    for (int e = eBeg + t; e < eEnd; e += 256)
        atomicAdd(&s[pairs[e] >> 24], 1);
    __syncthreads();
    const int v = s[t];
    #pragma unroll
    for (int off = 1; off < 256; off <<= 1) {
        int add = (t >= off) ? s[t - off] : 0;
        __syncthreads();
        s[t] += add;
        __syncthreads();
    }
    const int rp = eBeg + s[t] - v;
    const int node = nodeBase + t;
    if (node < N) {
        rowp[node] = rp;
        rowe[node] = rp + v;
        dinv[node] = rsqrtf((float)(v + 1));
    }
    cur[t] = rp;
    __syncthreads();
    for (int e = eBeg + t; e < eEnd; e += 256) {
        unsigned p = pairs[e];
        int pos = atomicAdd(&cur[p >> 24], 1);
        ssrc[pos] = (int)(p & 0xFFFFFFu);
    }
}

// ---------------- prep: w1t, w2t (both transposed bf16 [n][k] for MFMA),
//                  bucket cursors ----------------
__global__ __launch_bounds__(256) void prep_all(const float* __restrict__ W1,
                                                u16* __restrict__ w1t,
                                                const float* __restrict__ W2,
                                                u16* __restrict__ w2t,
                                                int* __restrict__ bcur, int B) {
    int idx = blockIdx.x * 256 + threadIdx.x;
    if (idx < 128 * 128) {
        int n = idx >> 7, k = idx & 127;
        w1t[idx] = f2bf(W1[k * 128 + n]);          // [n][k] for MFMA B-frags
    } else if (idx < 128 * 128 + 64 * 128) {
        int j = idx - 128 * 128;
        int n = j >> 7, k = j & 127;
        w2t[j] = f2bf(W2[k * 64 + n]);             // [n][k] for MFMA B-frags
    }
    if (idx < B) bcur[idx] = idx * BCAP;
}

// ---------------- MFMA GEMM (layer 1): g1 = bf16((x @ W1) * dinv[row]) ------
template <int FIN, int FOUT, bool AF32, int MINW>
__global__ __launch_bounds__(256, MINW)
void gemm_mfma(const void* __restrict__ Xv, const u16* __restrict__ Wt,
               const float* __restrict__ dinv, u16* __restrict__ G, int N) {
    constexpr int NT = FOUT / 16;
    constexpr int KK = FIN / 32;
    constexpr int CB = FIN / 8;
    constexpr int ITER = (64 * CB) / 256;
    __shared__ __align__(16) u16 xs[64 * FIN];
    __shared__ float ldv[64];

    const int t = threadIdx.x;
    const int wave = t >> 6;
    const int lane = t & 63;
    const int l15 = lane & 15;
    const int quad = lane >> 4;
    const int r0 = blockIdx.x * 64;

    bfrag Bf[NT][KK];
    #pragma unroll
    for (int nt = 0; nt < NT; nt++)
        #pragma unroll
        for (int kk = 0; kk < KK; kk++)
            Bf[nt][kk] = *reinterpret_cast<const bfrag*>(
                &Wt[(size_t)(nt * 16 + l15) * FIN + kk * 32 + quad * 8]);

    if (t < 64) ldv[t] = (r0 + t < N) ? dinv[r0 + t] : 0.f;

    #pragma unroll
    for (int i = 0; i < ITER; i++) {
        int v = t + 256 * i;
        int row = v / CB;
        int cb = v - row * CB;
        uint4 pack = make_uint4(0, 0, 0, 0);
        if (r0 + row < N) {
            if (AF32) {
                const float* X = (const float*)Xv;
                const float4* p = reinterpret_cast<const float4*>(
                    &X[(size_t)(r0 + row) * FIN + cb * 8]);
                float4 lo = p[0], hi = p[1];
                pack.x = f2bf(lo.x) | ((unsigned)f2bf(lo.y) << 16);
                pack.y = f2bf(lo.z) | ((unsigned)f2bf(lo.w) << 16);
                pack.z = f2bf(hi.x) | ((unsigned)f2bf(hi.y) << 16);
                pack.w = f2bf(hi.z) | ((unsigned)f2bf(hi.w) << 16);
            } else {
                const u16* X = (const u16*)Xv;
                pack = *reinterpret_cast<const uint4*>(
                    &X[(size_t)(r0 + row) * FIN + cb * 8]);
            }
        }
        int cbs = cb ^ (row & 7);
        *reinterpret_cast<uint4*>(&xs[row * FIN + cbs * 8]) = pack;
    }
    __syncthreads();

    ffrag acc[NT];
    #pragma unroll
    for (int nt = 0; nt < NT; nt++) {
        acc[nt][0] = 0.f; acc[nt][1] = 0.f; acc[nt][2] = 0.f; acc[nt][3] = 0.f;
    }

    const int arow = wave * 16 + l15;
    #pragma unroll
    for (int kk = 0; kk < KK; kk++) {
        int cb = (kk * 4 + quad) ^ (l15 & 7);
        bfrag a = *reinterpret_cast<const bfrag*>(&xs[arow * FIN + cb * 8]);
        #pragma unroll
        for (int nt = 0; nt < NT; nt++)
            acc[nt] = __builtin_amdgcn_mfma_f32_16x16x32_bf16(a, Bf[nt][kk], acc[nt], 0, 0, 0);
    }

    #pragma unroll
    for (int nt = 0; nt < NT; nt++)
        #pragma unroll
        for (int r = 0; r < 4; r++) {
            int rl = wave * 16 + quad * 4 + r;
            int grow = r0 + rl;
            if (grow < N)
                G[(size_t)grow * FOUT + nt * 16 + l15] = f2bf(acc[nt][r] * ldv[rl]);
        }
}

// ---------------- L1 aggregate + fused L2 GEMM via MFMA ----------------
// h1[d] = relu(dinv*(g1[d]+sum g1[src])+b1)  (bf16, staged in LDS)
// g2 tile = bf16(dinv[m] * (h1 @ W2)): 16 nodes x 64 cols, wave w does its
// 16-col tile with 4x mfma_16x16x32_bf16. A from LDS (stride 136 -> <=2-way),
// B-frags from w2t [n][k] (same verified pattern as gemm_mfma).
__global__ __launch_bounds__(256) void agg1_gemm2(const u16* __restrict__ G,
                                                  const int* __restrict__ rowp,
                                                  const int* __restrict__ rowe,
                                                  const int* __restrict__ ssrc,
                                                  const float* __restrict__ dinv,
                                                  const float* __restrict__ bias,
                                                  const u16* __restrict__ w2t,
                                                  u16* __restrict__ g2, int N) {
    __shared__ __align__(16) u16 hl[16][136];   // 4.25 KB, padded stride 272B
    __shared__ float ldv[16];
    const int t = threadIdx.x;
    const int wave = t >> 6;
    const int lane = t & 63;
    const int l15 = lane & 15;
    const int quad = lane >> 4;
    const int lj = t & 15;     // 16 lanes per node (8 features each)
    const int dn = t >> 4;     // node-in-block
    const int d0 = blockIdx.x * 16;
    const int d = d0 + dn;

    if (t < 16) ldv[t] = (d0 + t < N) ? dinv[d0 + t] : 0.f;

    uint4 pk = make_uint4(0, 0, 0, 0);
    if (d < N) {
        const uint4* G4 = reinterpret_cast<const uint4*>(G);
        float a[8];
        #pragma unroll
        for (int i = 0; i < 8; i++) a[i] = 0.f;
        bfacc8(a, G4[(size_t)d * 16 + lj]);   // self loop
        int e = rowp[d];
        const int end = rowe[d];
        for (; e + 8 <= end; e += 8) {
            int s0 = ssrc[e],     s1 = ssrc[e + 1], s2 = ssrc[e + 2], s3 = ssrc[e + 3];
            int s4 = ssrc[e + 4], s5 = ssrc[e + 5], s6 = ssrc[e + 6], s7 = ssrc[e + 7];
            uint4 u0 = G4[(size_t)s0 * 16 + lj];
            uint4 u1 = G4[(size_t)s1 * 16 + lj];
            uint4 u2 = G4[(size_t)s2 * 16 + lj];
            uint4 u3 = G4[(size_t)s3 * 16 + lj];
            uint4 u4 = G4[(size_t)s4 * 16 + lj];
            uint4 u5 = G4[(size_t)s5 * 16 + lj];
            uint4 u6 = G4[(size_t)s6 * 16 + lj];
            uint4 u7 = G4[(size_t)s7 * 16 + lj];
            bfacc8(a, u0); bfacc8(a, u1); bfacc8(a, u2); bfacc8(a, u3);
            bfacc8(a, u4); bfacc8(a, u5); bfacc8(a, u6); bfacc8(a, u7);
        }
        for (; e + 4 <= end; e += 4) {
            int s0 = ssrc[e], s1 = ssrc[e + 1], s2 = ssrc[e + 2], s3 = ssrc[e + 3];
            uint4 u0 = G4[(size_t)s0 * 16 + lj];
            uint4 u1 = G4[(size_t)s1 * 16 + lj];
            uint4 u2 = G4[(size_t)s2 * 16 + lj];
            uint4 u3 = G4[(size_t)s3 * 16 + lj];
            bfacc8(a, u0); bfacc8(a, u1); bfacc8(a, u2); bfacc8(a, u3);
        }
        for (; e < end; e++)
            bfacc8(a, G4[(size_t)ssrc[e] * 16 + lj]);
        const float dv = dinv[d];
        const float4 b0 = reinterpret_cast<const float4*>(bias)[lj * 2];
        const float4 b1 = reinterpret_cast<const float4*>(bias)[lj * 2 + 1];
        float h[8];
        h[0] = fmaxf(a[0] * dv + b0.x, 0.f);
        h[1] = fmaxf(a[1] * dv + b0.y, 0.f);
        h[2] = fmaxf(a[2] * dv + b0.z, 0.f);
        h[3] = fmaxf(a[3] * dv + b0.w, 0.f);
        h[4] = fmaxf(a[4] * dv + b1.x, 0.f);
        h[5] = fmaxf(a[5] * dv + b1.y, 0.f);
        h[6] = fmaxf(a[6] * dv + b1.z, 0.f);
        h[7] = fmaxf(a[7] * dv + b1.w, 0.f);
        pk.x = f2bf(h[0]) | ((unsigned)f2bf(h[1]) << 16);
        pk.y = f2bf(h[2]) | ((unsigned)f2bf(h[3]) << 16);
        pk.z = f2bf(h[4]) | ((unsigned)f2bf(h[5]) << 16);
        pk.w = f2bf(h[6]) | ((unsigned)f2bf(h[7]) << 16);
    }
    *reinterpret_cast<uint4*>(&hl[dn][lj * 8]) = pk;
    __syncthreads();

    // B-frags loaded post-barrier: keeps gather-phase VGPR low.
    bfrag Bf[4];
    #pragma unroll
    for (int kk = 0; kk < 4; kk++)
        Bf[kk] = *reinterpret_cast<const bfrag*>(
            &w2t[(size_t)(wave * 16 + l15) * 128 + kk * 32 + quad * 8]);

    // MFMA: A[m=l15][k=quad*8+j] from hl; D: row=quad*4+r, col=l15.
    ffrag acc;
    acc[0] = 0.f; acc[1] = 0.f; acc[2] = 0.f; acc[3] = 0.f;
    #pragma unroll
    for (int kk = 0; kk < 4; kk++) {
        bfrag av = *reinterpret_cast<const bfrag*>(&hl[l15][kk * 32 + quad * 8]);
        acc = __builtin_amdgcn_mfma_f32_16x16x32_bf16(av, Bf[kk], acc, 0, 0, 0);
    }
    #pragma unroll
    for (int r = 0; r < 4; r++) {
        int row = quad * 4 + r;
        int node = d0 + row;
        if (node < N)
            g2[(size_t)node * 64 + wave * 16 + l15] = f2bf(acc[r] * ldv[row]);
    }
}

// ---------------- L2 aggregate + fused L3 GEMV (fp32) ----------------
// h2[d] = relu(dinv*(g2[d]+sum g2[src])+b2)  (fp32)
// g3[d] = fp32(dinv[d] * (h2[d] @ W3))       (W3 fp32 [k][j] in LDS)
__global__ __launch_bounds__(256) void agg2_gemm3(const u16* __restrict__ G,
                                                  const int* __restrict__ rowp,
                                                  const int* __restrict__ rowe,
                                                  const int* __restrict__ ssrc,
                                                  const float* __restrict__ dinv,
                                                  const float* __restrict__ bias,
                                                  const float* __restrict__ W3,
                                                  float* __restrict__ g3, int N) {
    __shared__ __align__(16) float wl[64 * 32];   // 8 KB W3 [k][j]
    __shared__ __align__(16) float hl[32][68];    // padded: stride 272B
    const int t = threadIdx.x;
    {   // cooperative W3 load: 2048 floats = 512 float4
        const float4* s4 = reinterpret_cast<const float4*>(W3);
        float4* d4 = reinterpret_cast<float4*>(wl);
        d4[t] = s4[t];
        d4[t + 256] = s4[t + 256];
    }
    __syncthreads();
    const int lj = t & 7;      // 8 lanes per node (8 features each)
    const int dn = t >> 3;
    const int d = blockIdx.x * 32 + dn;
    if (d >= N) return;

    const uint4* G4 = reinterpret_cast<const uint4*>(G);
    float a[8];
    #pragma unroll
    for (int i = 0; i < 8; i++) a[i] = 0.f;
    bfacc8(a, G4[(size_t)d * 8 + lj]);   // self loop
    int e = rowp[d];
    const int end = rowe[d];
    for (; e + 8 <= end; e += 8) {
        int s0 = ssrc[e],     s1 = ssrc[e + 1], s2 = ssrc[e + 2], s3 = ssrc[e + 3];
        int s4 = ssrc[e + 4], s5 = ssrc[e + 5], s6 = ssrc[e + 6], s7 = ssrc[e + 7];
        uint4 u0 = G4[(size_t)s0 * 8 + lj];
        uint4 u1 = G4[(size_t)s1 * 8 + lj];
        uint4 u2 = G4[(size_t)s2 * 8 + lj];
        uint4 u3 = G4[(size_t)s3 * 8 + lj];
        uint4 u4 = G4[(size_t)s4 * 8 + lj];
        uint4 u5 = G4[(size_t)s5 * 8 + lj];
        uint4 u6 = G4[(size_t)s6 * 8 + lj];
        uint4 u7 = G4[(size_t)s7 * 8 + lj];
        bfacc8(a, u0); bfacc8(a, u1); bfacc8(a, u2); bfacc8(a, u3);
        bfacc8(a, u4); bfacc8(a, u5); bfacc8(a, u6); bfacc8(a, u7);
    }
    for (; e + 4 <= end; e += 4) {
        int s0 = ssrc[e], s1 = ssrc[e + 1], s2 = ssrc[e + 2], s3 = ssrc[e + 3];
        uint4 u0 = G4[(size_t)s0 * 8 + lj];
        uint4 u1 = G4[(size_t)s1 * 8 + lj];
        uint4 u2 = G4[(size_t)s2 * 8 + lj];
        uint4 u3 = G4[(size_t)s3 * 8 + lj];
        bfacc8(a, u0); bfacc8(a, u1); bfacc8(a, u2); bfacc8(a, u3);
    }
    for (; e < end; e++)
        bfacc8(a, G4[(size_t)ssrc[e] * 8 + lj]);
    const float dv = dinv[d];
    const float4 b0 = reinterpret_cast<const float4*>(bias)[lj * 2];
    const float4 b1 = reinterpret_cast<const float4*>(bias)[lj * 2 + 1];
    float h[8];
    h[0] = fmaxf(a[0] * dv + b0.x, 0.f);
    h[1] = fmaxf(a[1] * dv + b0.y, 0.f);
    h[2] = fmaxf(a[2] * dv + b0.z, 0.f);
    h[3] = fmaxf(a[3] * dv + b0.w, 0.f);
    h[4] = fmaxf(a[4] * dv + b1.x, 0.f);
    h[5] = fmaxf(a[5] * dv + b1.y, 0.f);
    h[6] = fmaxf(a[6] * dv + b1.z, 0.f);
    h[7] = fmaxf(a[7] * dv + b1.w, 0.f);
    *reinterpret_cast<float4*>(&hl[dn][lj * 8])     = make_float4(h[0], h[1], h[2], h[3]);
    *reinterpret_cast<float4*>(&hl[dn][lj * 8 + 4]) = make_float4(h[4], h[5], h[6], h[7]);
    // GEMV: 8-lane group intra-wave -> ordered LDS, no barrier.
    float g[4] = {0.f, 0.f, 0.f, 0.f};
    #pragma unroll 4
    for (int k4 = 0; k4 < 16; k4++) {
        float4 hv = *reinterpret_cast<const float4*>(&hl[dn][k4 * 4]);
        float hs[4] = {hv.x, hv.y, hv.z, hv.w};
        #pragma unroll
        for (int p = 0; p < 4; p++) {
            float4 w = *reinterpret_cast<const float4*>(&wl[(k4 * 4 + p) * 32 + lj * 4]);
            g[0] += hs[p] * w.x; g[1] += hs[p] * w.y;
            g[2] += hs[p] * w.z; g[3] += hs[p] * w.w;
        }
    }
    *reinterpret_cast<float4*>(&g3[(size_t)d * 32 + lj * 4]) =
        make_float4(g[0] * dv, g[1] * dv, g[2] * dv, g[3] * dv);
}

// ---------------- L3 aggregate fused with edge-score node dots ----------------
__global__ __launch_bounds__(256) void aggregate_l3s(const float* __restrict__ G,
                                                     const int* __restrict__ rowp,
                                                     const int* __restrict__ rowe,
                                                     const int* __restrict__ ssrc,
                                                     const float* __restrict__ dinv,
                                                     const float* __restrict__ bias,
                                                     const float* __restrict__ Wc,
                                                     float2* __restrict__ ab, int N) {
    constexpr int L = 8;
    const int t = threadIdx.x;
    const int lj = t % L;
    const int d = blockIdx.x * 32 + t / L;
    if (d >= N) return;

    const float4* G4 = reinterpret_cast<const float4*>(G);
    float4 acc = G4[(size_t)d * L + lj];
    int e = rowp[d];
    const int end = rowe[d];
    for (; e + 8 <= end; e += 8) {
        int s0 = ssrc[e],     s1 = ssrc[e + 1], s2 = ssrc[e + 2], s3 = ssrc[e + 3];
        int s4 = ssrc[e + 4], s5 = ssrc[e + 5], s6 = ssrc[e + 6], s7 = ssrc[e + 7];
        float4 v0 = G4[(size_t)s0 * L + lj];
        float4 v1 = G4[(size_t)s1 * L + lj];
        float4 v2 = G4[(size_t)s2 * L + lj];
        float4 v3 = G4[(size_t)s3 * L + lj];
        float4 v4 = G4[(size_t)s4 * L + lj];
        float4 v5 = G4[(size_t)s5 * L + lj];
        float4 v6 = G4[(size_t)s6 * L + lj];
        float4 v7 = G4[(size_t)s7 * L + lj];
        acc = f4add(acc, f4add(f4add(f4add(v0, v1), f4add(v2, v3)),
                               f4add(f4add(v4, v5), f4add(v6, v7))));
    }
    for (; e + 4 <= end; e += 4) {
        int s0 = ssrc[e], s1 = ssrc[e + 1], s2 = ssrc[e + 2], s3 = ssrc[e + 3];
        float4 v0 = G4[(size_t)s0 * L + lj];
        float4 v1 = G4[(size_t)s1 * L + lj];
        float4 v2 = G4[(size_t)s2 * L + lj];
        float4 v3 = G4[(size_t)s3 * L + lj];
        acc = f4add(acc, f4add(f4add(v0, v1), f4add(v2, v3)));
    }
    for (; e < end; e++)
        acc = f4add(acc, G4[(size_t)ssrc[e] * L + lj]);
    const float dv = dinv[d];
    const float4 b4 = reinterpret_cast<const float4*>(bias)[lj];
    float4 h;
    h.x = fmaxf(acc.x * dv + b4.x, 0.f);
    h.y = fmaxf(acc.y * dv + b4.y, 0.f);
    h.z = fmaxf(acc.z * dv + b4.z, 0.f);
    h.w = fmaxf(acc.w * dv + b4.w, 0.f);
    const float4 wa = reinterpret_cast<const float4*>(Wc)[lj];
    const float4 wb = reinterpret_cast<const float4*>(Wc + 32)[lj];
    float p = h.x * wa.x + h.y * wa.y + h.z * wa.z + h.w * wa.w;
    float q = h.x * wb.x + h.y * wb.y + h.z * wb.z + h.w * wb.w;
    p += __shfl_xor(p, 1); q += __shfl_xor(q, 1);
    p += __shfl_xor(p, 2); q += __shfl_xor(q, 2);
    p += __shfl_xor(p, 4); q += __shfl_xor(q, 4);
    if (lj == 0) ab[d] = make_float2(p, q);
}

// ---------------- edge output ----------------

__global__ __launch_bounds__(256) void edge_out(const int* __restrict__ src,
                                                const int* __restrict__ dst,
                                                const float2* __restrict__ ab,
                                                const float* __restrict__ bc,
                                                float* __restrict__ out, int E) {
    int e = blockIdx.x * 256 + threadIdx.x;
    if (e < E) out[e] = ab[src[e]].x + ab[dst[e]].y + bc[0];
}

extern "C" void kernel_launch(void* const* d_in, const int* in_sizes, int n_in,
                              void* d_out, int out_size, void* d_ws, size_t ws_size,
                              hipStream_t stream) {
    const float* x  = (const float*)d_in[0];
    const int*   ei = (const int*)d_in[1];
    const float* W1 = (const float*)d_in[2];
    const float* b1 = (const float*)d_in[3];
    const float* W2 = (const float*)d_in[4];
    const float* b2 = (const float*)d_in[5];
    const float* W3 = (const float*)d_in[6];
    const float* b3 = (const float*)d_in[7];
    const float* Wc = (const float*)d_in[8];
    const float* bc = (const float*)d_in[9];
    float* out = (float*)d_out;

    const int N = in_sizes[0] / 128;   // 100000
    const int E = in_sizes[1] / 2;     // 1600000
    const int B = (N + 255) >> BSHIFT; // 391
    const int* src = ei;
    const int* dst = ei + E;

    size_t off = 0;
    auto alloc = [&](size_t bytes) -> void* {
        size_t o = (off + 255) & ~(size_t)255;
        off = o + bytes;
        return (void*)((char*)d_ws + o);
    };
    float* dinv = (float*)alloc((size_t)N * 4);
    int*   rowp = (int*)alloc((size_t)N * 4);
    int*   rowe = (int*)alloc((size_t)N * 4);
    int*   bcur = (int*)alloc((size_t)(B + 1) * 4);
    int*   ssrc = (int*)alloc((size_t)B * BCAP * 4);  // padded CSR storage
    u16*   w1t  = (u16*)alloc(128 * 128 * 2);
    u16*   w2t  = (u16*)alloc(64 * 128 * 2);
    u16*   g16  = (u16*)alloc((size_t)N * 128 * 2);   // L1 messages; g3f alias
    u16*   g2b  = (u16*)alloc((size_t)N * 64 * 2);    // L2 messages; pairs alias
    float2* ab  = (float2*)alloc((size_t)N * 8);
    (void)ws_size; (void)n_in; (void)out_size;

    unsigned* pairs = (unsigned*)g2b;  // 7.2MB pairs, dead before agg1 writes g2b
    float* g3f = (float*)g16;          // g16 dead after agg1_gemm2

    const int gE = (E + 255) / 256;
    const int gR = (N + 63) / 64;   // 1563

    prep_all<<<96, 256, 0, stream>>>(W1, w1t, W2, w2t, bcur, B);
    bin_edges<<<(E + BIN_CHUNK - 1) / BIN_CHUNK, 256, 0, stream>>>(src, dst, bcur, pairs, E, B);
    build_csr<<<B, 256, 0, stream>>>(pairs, bcur, rowp, rowe, dinv, ssrc, N);

    // layer 1 GEMM: x(f32,128) -> MFMA -> g16 (bf16 messages)
    gemm_mfma<128, 128, true, 2><<<gR, 256, 0, stream>>>(x, w1t, dinv, g16, N);
    // L1 aggregate + fused L2 MFMA-GEMM -> g2 (bf16 messages)
    agg1_gemm2<<<(N + 15) / 16, 256, 0, stream>>>(g16, rowp, rowe, ssrc, dinv, b1, w2t, g2b, N);
    // L2 aggregate + fused L3 GEMV -> g3 (fp32 messages)
    agg2_gemm3<<<(N + 31) / 32, 256, 0, stream>>>(g2b, rowp, rowe, ssrc, dinv, b2, W3, g3f, N);
    // L3 aggregate + edge-score node dots
    aggregate_l3s<<<(N + 31) / 32, 256, 0, stream>>>(g3f, rowp, rowe, ssrc, dinv, b3, Wc, ab, N);

    // edge output
    edge_out<<<gE, 256, 0, stream>>>(src, dst, ab, bc, out, E);
}